// Round 4
// baseline (991.129 us; speedup 1.0000x reference)
//
#include <hip/hip_runtime.h>

typedef __attribute__((ext_vector_type(8))) short bf16x8;
typedef __attribute__((ext_vector_type(4))) short s16x4;
typedef __attribute__((ext_vector_type(4))) float f32x4;
typedef __attribute__((ext_vector_type(2))) unsigned int u32x2;
typedef unsigned short ushort_t;

#define LOG2E 1.44269504088896340736f

// ---------- helpers ----------
__device__ __forceinline__ unsigned short f2bf(float x) {
  unsigned int u = __float_as_uint(x);
  u = (u + 0x7FFFu + ((u >> 16) & 1u)) >> 16;   // RNE
  return (unsigned short)u;
}

// pack two f32 -> two bf16 (round-half-up) in one v_perm_b32
__device__ __forceinline__ unsigned pack2(float a, float b) {
  return __builtin_amdgcn_perm(__float_as_uint(b) + 0x8000u,
                               __float_as_uint(a) + 0x8000u, 0x07060302u);
}

__device__ __forceinline__ void async16(void* lds_dst, const void* gsrc) {
  __builtin_amdgcn_global_load_lds(
      (const __attribute__((address_space(1))) void*)gsrc,
      (__attribute__((address_space(3))) void*)lds_dst, 16, 0, 0);
}

// ---------- fp32 -> bf16 row-major (vectorized) ----------
__global__ __launch_bounds__(256) void f32_to_bf16_vec(
    const float* __restrict__ in, ushort_t* __restrict__ out, int n8) {
  int i = blockIdx.x * 256 + threadIdx.x;
  if (i >= n8) return;
  const float4* p = (const float4*)in + (size_t)i * 2;
  float4 a = p[0], b = p[1];
  bf16x8 v;
  v[0] = (short)f2bf(a.x); v[1] = (short)f2bf(a.y);
  v[2] = (short)f2bf(a.z); v[3] = (short)f2bf(a.w);
  v[4] = (short)f2bf(b.x); v[5] = (short)f2bf(b.y);
  v[6] = (short)f2bf(b.z); v[7] = (short)f2bf(b.w);
  *((bf16x8*)out + i) = v;
}

// ---------- transpose fp32 (Kd x N) -> bf16 (Npad x Kd), zero-pad rows >= N ----------
__global__ __launch_bounds__(256) void transpose_w_bf16(
    const float* __restrict__ in, ushort_t* __restrict__ out, int N, int Kd) {
  __shared__ float tile[32][33];
  const int tx = threadIdx.x & 31, ty = threadIdx.x >> 5;
  const int n0 = blockIdx.x * 32, k0 = blockIdx.y * 32;
#pragma unroll
  for (int yy = 0; yy < 32; yy += 8) {
    int k = k0 + ty + yy;
    int n = n0 + tx;
    tile[ty + yy][tx] = (n < N) ? in[(size_t)k * N + n] : 0.f;
  }
  __syncthreads();
#pragma unroll
  for (int yy = 0; yy < 32; yy += 8) {
    int n = n0 + ty + yy;
    int k = k0 + tx;
    out[(size_t)n * Kd + k] = f2bf(tile[tx][ty + yy]);
  }
}

// ---------- 128x128-tile bf16 GEMM, split-K over blockIdx.z ----------
// C must be zero-initialized; each K-half unsafeAtomicAdd's its partial (fp32 add
// is commutative -> deterministic for 2 contributions).
__global__ __launch_bounds__(256) void gemm_bt_128(
    const ushort_t* __restrict__ A, const ushort_t* __restrict__ Bt,
    float* __restrict__ C, int N, int K, int ldc) {
  __shared__ __align__(16) char lds[16384];          // A: [0,8K), B: [8K,16K)
  const int tid = threadIdx.x;
  const int lane = tid & 63, wave = tid >> 6;
  const int quad = lane >> 4, col = lane & 15;
  const int bm = blockIdx.x, bn = blockIdx.y;
  const int wr = (wave >> 1) * 64, wc = (wave & 1) * 64;

  const int Kh = K >> 1;                             // split-K=2
  const size_t kofs = (size_t)blockIdx.z * Kh;

  const int c0 = tid, c1 = tid + 256;
  const int r0 = c0 >> 2, r1 = c1 >> 2;
  const int l0 = (c0 & 3) ^ ((r0 >> 1) & 3);
  const int l1 = (c1 & 3) ^ ((r1 >> 1) & 3);
  const ushort_t* a0 = A + kofs + (size_t)(bm * 128 + r0) * K + l0 * 8;
  const ushort_t* a1 = A + kofs + (size_t)(bm * 128 + r1) * K + l1 * 8;
  const ushort_t* b0 = Bt + kofs + (size_t)(bn * 128 + r0) * K + l0 * 8;
  const ushort_t* b1 = Bt + kofs + (size_t)(bn * 128 + r1) * K + l1 * 8;
  const int wb = wave * 1024;

  f32x4 acc[4][4];
#pragma unroll
  for (int i = 0; i < 4; ++i)
#pragma unroll
    for (int j = 0; j < 4; ++j) acc[i][j] = (f32x4){0.f, 0.f, 0.f, 0.f};

  const int ccsw = (col >> 1) & 3;
  int aoff[4], boff[4];
#pragma unroll
  for (int t = 0; t < 4; ++t) {
    aoff[t] = (wr + t * 16 + col) * 64 + ((quad ^ ccsw) << 4);
    boff[t] = 8192 + (wc + t * 16 + col) * 64 + ((quad ^ ccsw) << 4);
  }

#pragma unroll 1
  for (int k = 0; k < Kh; k += 32) {
    __syncthreads();
    async16(lds + wb,           a0 + k);
    async16(lds + wb + 4096,    a1 + k);
    async16(lds + 8192 + wb,        b0 + k);
    async16(lds + 8192 + wb + 4096, b1 + k);
    __syncthreads();
    bf16x8 af[4], bfr[4];
#pragma unroll
    for (int t = 0; t < 4; ++t) {
      af[t]  = *(const bf16x8*)(lds + aoff[t]);
      bfr[t] = *(const bf16x8*)(lds + boff[t]);
    }
#pragma unroll
    for (int i = 0; i < 4; ++i)
#pragma unroll
      for (int j = 0; j < 4; ++j)
        acc[i][j] = __builtin_amdgcn_mfma_f32_16x16x32_bf16(af[i], bfr[j], acc[i][j], 0, 0, 0);
  }

#pragma unroll
  for (int i = 0; i < 4; ++i) {
    const int row = bm * 128 + wr + i * 16 + quad * 4;
#pragma unroll
    for (int j = 0; j < 4; ++j) {
      const int cc = bn * 128 + wc + j * 16 + col;
      if (cc < N) {
#pragma unroll
        for (int r = 0; r < 4; ++r)
          unsafeAtomicAdd(&C[(size_t)(row + r) * ldc + cc], acc[i][j][r]);
      }
    }
  }
}

// ---------- RoPE + split fused(2048x4672) -> Qr(/8, bf16), Kr, Vt; zero ssum ----------
__global__ __launch_bounds__(256) void rope_split(
    const float* __restrict__ fused, ushort_t* __restrict__ Qr,
    ushort_t* __restrict__ Kr, ushort_t* __restrict__ Vt, float* __restrict__ ssum) {
  const int spos = blockIdx.x;
  const float* row = fused + (size_t)spos * 4672;
  if (blockIdx.x == 0)
    for (int j = threadIdx.x; j < 2048; j += 256) ssum[j] = 0.f;
  for (int c = threadIdx.x; c < 4672; c += 256) {
    const int hh = c >> 6, d = c & 63, j = d & 31;
    const float x = row[c];
    if (hh == 72) { Vt[(size_t)d * 2048 + spos] = f2bf(x); continue; }
    const float freq = powf(10000.0f, -(float)j * (1.0f / 32.0f));
    const float ang = (float)spos * freq;
    const float cv = cosf(ang), sv = sinf(ang);
    const float partner = (d < 32) ? row[c + 32] : row[c - 32];
    const float val = (d < 32) ? (x * cv - partner * sv) : (x * cv + partner * sv);
    if (hh == 71) Kr[(size_t)spos * 64 + d] = f2bf(val);
    else          Qr[(size_t)spos * 4544 + c] = f2bf(val * 0.125f);  // fold 1/sqrt(64)
  }
}

// ---------- flash MQA attention, fixed-base softmax, paired query blocks ----------
// Block x handles qb = 15-x then qb = x  ->  every block does exactly 17 work
// units (uniform grid of 8 x 71). Sweep 1: S^T = K·Q^T, p = exp2((s-16)*log2e)
// (diagonal guarantees s_max >= 0: no running max needed), P^T -> pbuf, O^T =
// V^T·P^T. Mask compare only on the diagonal 16x16 tile; fully-masked tiles skip
// MFMA and write zero P. Sweep 2: QK^T recompute, normalized colsums.
__global__ __launch_bounds__(256) void attn_flash(
    const ushort_t* __restrict__ Qr, const ushort_t* __restrict__ Kr,
    const ushort_t* __restrict__ Vt, ushort_t* __restrict__ merged,
    float* __restrict__ ssum) {
  const int h = blockIdx.y;
  const int tid = threadIdx.x, wave = tid >> 6, lane = tid & 63;
  const int quad = lane >> 4, col = lane & 15;

  __shared__ __align__(16) ushort_t kbuf[64 * 72];
  __shared__ __align__(16) ushort_t vbuf[64 * 72];
  __shared__ __align__(16) char pcs[4 * 32 * 72 * 2];    // pbuf (s1) / cs (s2)
  ushort_t* pbuf = (ushort_t*)pcs + wave * (32 * 72);    // P^T: [32 q][64 k] stride 72
  float* cs = (float*)pcs;

  const int c0 = tid * 2;
  const int srow = c0 >> 3, sg = c0 & 7;
  const int thr = col - quad * 4;        // diag mask: key<=q  <=>  r <= thr

#pragma unroll 1
  for (int half = 0; half < 2; ++half) {
    const int qb = half ? (int)blockIdx.x : 15 - (int)blockIdx.x;
    const int q0 = qb * 128;
    const int qw = q0 + wave * 32;
    const int ntiles = (qb + 1) * 2;

    // Q fragments: rows qw+nt*16+col (B-op in sweep1, A-op in sweep2)
    bf16x8 qf[2][2];
#pragma unroll
    for (int nt = 0; nt < 2; ++nt)
#pragma unroll
      for (int s = 0; s < 2; ++s)
        qf[nt][s] = *(const bf16x8*)(Qr + (size_t)(qw + nt * 16 + col) * 4544 + h * 64 + s * 32 + quad * 8);

    f32x4 oacc[2][4];                                    // [q-tile][d-tile] of O^T
    float l[2] = {0.f, 0.f};
#pragma unroll
    for (int nt = 0; nt < 2; ++nt)
#pragma unroll
      for (int m = 0; m < 4; ++m) oacc[nt][m] = (f32x4){0.f, 0.f, 0.f, 0.f};

    // ---- sweep 1 ----
#pragma unroll 1
    for (int t = 0; t < ntiles; ++t) {
      const int kbase = t * 64;
      __syncthreads();
      {
        const ushort_t* ks = Kr + (size_t)(kbase + srow) * 64 + sg * 8;
        ushort_t* kd = kbuf + srow * 72 + sg * 8;
        *(bf16x8*)kd = *(const bf16x8*)ks;
        *(bf16x8*)(kd + 8) = *(const bf16x8*)(ks + 8);
        const ushort_t* vs = Vt + (size_t)srow * 2048 + kbase + sg * 8;
        ushort_t* vd = vbuf + srow * 72 + sg * 8;
        *(bf16x8*)vd = *(const bf16x8*)vs;
        *(bf16x8*)(vd + 8) = *(const bf16x8*)(vs + 8);
      }
      __syncthreads();
      if (kbase > qw + 16) continue;                     // wave fully masked

      bf16x8 kf[4][2];                                   // A-frags: rows = keys
#pragma unroll
      for (int m = 0; m < 4; ++m) {
        if (kbase + m * 16 <= qw + 16) {
          kf[m][0] = *(const bf16x8*)(kbuf + (m * 16 + col) * 72 + quad * 8);
          kf[m][1] = *(const bf16x8*)(kbuf + (m * 16 + col) * 72 + 32 + quad * 8);
        }
      }
#pragma unroll
      for (int nt = 0; nt < 2; ++nt) {
        const int qmin = qw + nt * 16;
        if (kbase > qmin) continue;
        float lacc = 0.f;
#pragma unroll
        for (int m = 0; m < 4; ++m) {
          const int kb2 = kbase + m * 16;
          u32x2 pk;
          if (kb2 > qmin) {
            pk = (u32x2){0u, 0u};                        // masked tile: zero P
          } else {
            f32x4 sacc = (f32x4){0.f, 0.f, 0.f, 0.f};
            sacc = __builtin_amdgcn_mfma_f32_16x16x32_bf16(kf[m][0], qf[nt][0], sacc, 0, 0, 0);
            sacc = __builtin_amdgcn_mfma_f32_16x16x32_bf16(kf[m][1], qf[nt][1], sacc, 0, 0, 0);
            float p[4];
            if (kb2 == qmin) {                           // diagonal tile: mask
#pragma unroll
              for (int r = 0; r < 4; ++r)
                p[r] = (r <= thr) ? __builtin_amdgcn_exp2f((sacc[r] - 16.f) * LOG2E) : 0.f;
            } else {                                     // full tile: no mask
#pragma unroll
              for (int r = 0; r < 4; ++r)
                p[r] = __builtin_amdgcn_exp2f((sacc[r] - 16.f) * LOG2E);
            }
            lacc += (p[0] + p[1]) + (p[2] + p[3]);
            pk[0] = pack2(p[0], p[1]);
            pk[1] = pack2(p[2], p[3]);
          }
          *(u32x2*)(pbuf + (nt * 16 + col) * 72 + m * 16 + quad * 4) = pk;
        }
        l[nt] += lacc;
      }
      // PV: O^T += V^T · P^T
#pragma unroll
      for (int ch = 0; ch < 2; ++ch) {
        if (kbase + ch * 32 > qw + 31) continue;
        bf16x8 vf[4];
#pragma unroll
        for (int m = 0; m < 4; ++m)
          vf[m] = *(const bf16x8*)(vbuf + (m * 16 + col) * 72 + ch * 32 + quad * 8);
#pragma unroll
        for (int nt = 0; nt < 2; ++nt) {
          if (kbase + ch * 32 > qw + nt * 16 + 15) continue;
          const bf16x8 pf = *(const bf16x8*)(pbuf + (nt * 16 + col) * 72 + ch * 32 + quad * 8);
#pragma unroll
          for (int m = 0; m < 4; ++m)
            oacc[nt][m] = __builtin_amdgcn_mfma_f32_16x16x32_bf16(vf[m], pf, oacc[nt][m], 0, 0, 0);
        }
      }
    }

    // l reduce across quads (per-lane partials cover keys quad*4+r mod 16)
    float invl[2];
#pragma unroll
    for (int nt = 0; nt < 2; ++nt) {
      float v = l[nt];
      v += __shfl_xor(v, 16, 64);
      v += __shfl_xor(v, 32, 64);
      invl[nt] = 1.0f / v;
    }

    // write O^T (lane holds 4 consecutive d for query nt*16+col)
#pragma unroll
    for (int nt = 0; nt < 2; ++nt)
#pragma unroll
      for (int m = 0; m < 4; ++m) {
        u32x2 ok;
        ok[0] = pack2(oacc[nt][m][0] * invl[nt], oacc[nt][m][1] * invl[nt]);
        ok[1] = pack2(oacc[nt][m][2] * invl[nt], oacc[nt][m][3] * invl[nt]);
        *(u32x2*)(merged + (size_t)(qw + nt * 16 + col) * 4544 + h * 64 + m * 16 + quad * 4) = ok;
      }

    // invl in sweep-2 row layout: query = qw + i*16 + quad*4 + r
    float linv2[2][4];
#pragma unroll
    for (int i = 0; i < 2; ++i)
#pragma unroll
      for (int r = 0; r < 4; ++r) linv2[i][r] = __shfl(invl[i], quad * 4 + r, 16);

    // ---- sweep 2: normalized colsums ----
    __syncthreads();                                 // pbuf reads done -> reuse as cs
    const int nk = ntiles * 64;
    for (int j = tid; j < nk; j += 256) cs[j] = 0.f;

#pragma unroll 1
    for (int t = 0; t < ntiles; ++t) {
      const int kbase = t * 64;
      __syncthreads();
      {
        const ushort_t* ks = Kr + (size_t)(kbase + srow) * 64 + sg * 8;
        ushort_t* kd = kbuf + srow * 72 + sg * 8;
        *(bf16x8*)kd = *(const bf16x8*)ks;
        *(bf16x8*)(kd + 8) = *(const bf16x8*)(ks + 8);
      }
      __syncthreads();
      if (kbase > qw + 16) continue;

      bf16x8 kf[4][2];                               // B-frags: rows = keys
#pragma unroll
      for (int n = 0; n < 4; ++n) {
        if (kbase + n * 16 <= qw + 16) {
          kf[n][0] = *(const bf16x8*)(kbuf + (n * 16 + col) * 72 + quad * 8);
          kf[n][1] = *(const bf16x8*)(kbuf + (n * 16 + col) * 72 + 32 + quad * 8);
        }
      }
      float accn[4] = {0.f, 0.f, 0.f, 0.f};
#pragma unroll
      for (int i = 0; i < 2; ++i) {
        const int qmin = qw + i * 16;
        if (kbase > qmin) continue;
#pragma unroll
        for (int n = 0; n < 4; ++n) {
          const int kb2 = kbase + n * 16;
          if (kb2 > qmin) continue;                  // fully masked: skip MFMA too
          f32x4 sacc = (f32x4){0.f, 0.f, 0.f, 0.f};
          sacc = __builtin_amdgcn_mfma_f32_16x16x32_bf16(qf[i][0], kf[n][0], sacc, 0, 0, 0);
          sacc = __builtin_amdgcn_mfma_f32_16x16x32_bf16(qf[i][1], kf[n][1], sacc, 0, 0, 0);
          if (kb2 == qmin) {                         // diagonal: col <= quad*4+r
#pragma unroll
            for (int r = 0; r < 4; ++r) {
              if (col <= quad * 4 + r)
                accn[n] += __builtin_amdgcn_exp2f((sacc[r] - 16.f) * LOG2E) * linv2[i][r];
            }
          } else {
#pragma unroll
            for (int r = 0; r < 4; ++r)
              accn[n] += __builtin_amdgcn_exp2f((sacc[r] - 16.f) * LOG2E) * linv2[i][r];
          }
        }
      }
#pragma unroll
      for (int n = 0; n < 4; ++n) {
        float v = accn[n];
        v += __shfl_xor(v, 16, 64);
        v += __shfl_xor(v, 32, 64);
        if (quad == 0) atomicAdd(&cs[kbase + n * 16 + col], v);
      }
    }

    __syncthreads();
    for (int j = tid; j < nk; j += 256) atomicAdd(&ssum[j], cs[j]);
    __syncthreads();                                 // cs reads done before next half
  }
}

// ---------- top-k(128) of ssum[0..1919] -> mask (2049 floats) ----------
__global__ __launch_bounds__(1024) void topk_mask(
    const float* __restrict__ ssum, float* __restrict__ maskout) {
  __shared__ float sv[1920];
  for (int i = threadIdx.x; i < 1920; i += 1024) sv[i] = ssum[i];
  __syncthreads();
  for (int i = threadIdx.x; i < 2049; i += 1024) {
    float o;
    if (i >= 1921) o = 1.f;
    else if (i == 1920) o = 0.f;
    else {
      const float v = sv[i];
      int rank = 0;
      for (int j = 0; j < 1920; ++j) {
        const float w = sv[j];
        rank += (w > v) || (w == v && j < i);
      }
      o = (rank < 128) ? 1.f : 0.f;
    }
    maskout[i] = o;
  }
}

// ---------- launch ----------
extern "C" void kernel_launch(void* const* d_in, const int* in_sizes, int n_in,
                              void* d_out, int out_size, void* d_ws, size_t ws_size,
                              hipStream_t stream) {
  (void)in_sizes; (void)n_in; (void)out_size; (void)ws_size;
  const float* hs      = (const float*)d_in[0];   // 1x2048x4544
  const float* w_qkv   = (const float*)d_in[1];   // 4544x4672
  const float* w_dense = (const float*)d_in[2];   // 4544x4544
  float* out = (float*)d_out;                     // 2048*4544 + 2049

  char* ws = (char*)d_ws;
  constexpr size_t OFF_WT    = 0;                        // 4736x4544 bf16
  constexpr size_t OFF_HSB   = 43040768;                 // 2048x4544 bf16 (reused as merged)
  constexpr size_t OFF_FUSED = OFF_HSB + 18612224;       // 2048x4672 fp32
  constexpr size_t OFF_QR    = OFF_FUSED + 38273024;     // 2048x4544 bf16
  constexpr size_t OFF_KR    = OFF_QR + 18612224;        // 2048x64 bf16
  constexpr size_t OFF_VT    = OFF_KR + 262144;          // 64x2048 bf16
  constexpr size_t OFF_SS    = OFF_VT + 262144;          // 2048 fp32

  ushort_t* wT     = (ushort_t*)(ws + OFF_WT);
  ushort_t* hsb    = (ushort_t*)(ws + OFF_HSB);
  float*    fused  = (float*)(ws + OFF_FUSED);
  ushort_t* qr     = (ushort_t*)(ws + OFF_QR);
  ushort_t* kr     = (ushort_t*)(ws + OFF_KR);
  ushort_t* vt     = (ushort_t*)(ws + OFF_VT);
  float*    ssum   = (float*)(ws + OFF_SS);

  // zero split-K accumulation targets
  hipMemsetAsync(fused, 0, (size_t)2048 * 4672 * 4, stream);
  hipMemsetAsync(out, 0, (size_t)2048 * 4544 * 4, stream);

  f32_to_bf16_vec<<<4544, 256, 0, stream>>>(hs, hsb, 2048 * 4544 / 8);
  transpose_w_bf16<<<dim3(148, 142), 256, 0, stream>>>(w_qkv, wT, 4672, 4544);
  gemm_bt_128<<<dim3(16, 37, 2), 256, 0, stream>>>(hsb, wT, fused, 4672, 4544, 4672);
  rope_split<<<2048, 256, 0, stream>>>(fused, qr, kr, vt, ssum);
  transpose_w_bf16<<<dim3(144, 142), 256, 0, stream>>>(w_dense, wT, 4544, 4544);
  attn_flash<<<dim3(8, 71), 256, 0, stream>>>(qr, kr, vt, hsb, ssum);
  topk_mask<<<1, 1024, 0, stream>>>(ssum, out + (size_t)2048 * 4544);
  gemm_bt_128<<<dim3(16, 36, 2), 256, 0, stream>>>(hsb, wT, out, 4544, 4544, 4544);
}